// Round 8
// baseline (631.545 us; speedup 1.0000x reference)
//
#include <hip/hip_runtime.h>

#define WS7    7
#define SHIFT3 3
#define NHEAD  6
#define CCH    192
#define HDIM   32
#define HH56   56
#define LTOK   (HH56*HH56)      // 3136
#define NWIN   64
#define NBATCH 32
#define NWTOT  (NBATCH*NWIN)    // 2048
#define LW     49
#define MTOK   (NWTOT*LW)       // 100352

typedef unsigned short u16;
typedef unsigned int   u32;
typedef __bf16 b16;
typedef b16   b16x8 __attribute__((ext_vector_type(8)));
typedef u16   u16x8 __attribute__((ext_vector_type(8)));
typedef float f32x4 __attribute__((ext_vector_type(4)));

__device__ __forceinline__ float b2f(u16 u) {
    u32 x = ((u32)u) << 16;
    return __builtin_bit_cast(float, x);
}
__device__ __forceinline__ u16 f2b(float f) {
    u32 x = __builtin_bit_cast(u32, f);
    u32 r = x + 0x7FFFu + ((x >> 16) & 1u);
    return (u16)(r >> 16);
}
__device__ __forceinline__ float gelu_exact(float x) {
    return 0.5f * x * (1.0f + erff(x * 0.7071067811865475f));
}

// token m (window-order) -> (b, l) image order (bijection)
__device__ __forceinline__ int map_token(int m, int &b) {
    int widx = m / LW, p = m - widx * LW;
    b = widx >> 6;
    int wloc = widx & 63;
    int wh = wloc >> 3, ww = wloc & 7;
    int i = p / WS7, j = p - i * WS7;
    int gh = wh * WS7 + i + SHIFT3; if (gh >= HH56) gh -= HH56;
    int gw = ww * WS7 + j + SHIFT3; if (gw >= HH56) gw -= HH56;
    return gh * HH56 + gw;
}

// ---- dtype probe: flag=1 if x is fp32 storage, 0 if bf16 storage.
__global__ __launch_bounds__(1024) void probe_kernel(const u16* __restrict__ x, int* flag) {
    __shared__ int ch, cz;
    if (threadIdx.x == 0) { ch = 0; cz = 0; }
    __syncthreads();
    int i = threadIdx.x * 16;
    u16x8 a = *(const u16x8*)(x + i);
    u16x8 b = *(const u16x8*)(x + i + 8);
    int h = 0, z = 0;
    #pragma unroll
    for (int q = 0; q < 8; q++) {
        h += (((a[q] >> 7) & 0xFF) >= 0xC0) + (((b[q] >> 7) & 0xFF) >= 0xC0);
        z += (a[q] == 0) + (b[q] == 0);
    }
    #pragma unroll
    for (int off = 32; off > 0; off >>= 1) {
        h += __shfl_xor(h, off, 64);
        z += __shfl_xor(z, off, 64);
    }
    if ((threadIdx.x & 63) == 0) { atomicAdd(&ch, h); atomicAdd(&cz, z); }
    __syncthreads();
    if (threadIdx.x == 0) *flag = (ch > 250 || cz > 2048) ? 1 : 0;
}

// ---- canonicalize ALL param tensors to bf16 in ONE launch.
#define CANON_TOTAL 445302
__global__ __launch_bounds__(256) void canon_all_kernel(
    const int* __restrict__ flag,
    const void* s0, const void* s1, const void* s2,  const void* s3,
    const void* s4, const void* s5, const void* s6,  const void* s7,
    const void* s8, const void* s9, const void* s10, const void* s11,
    char* __restrict__ ws)
{
    int i = blockIdx.x * 256 + threadIdx.x;
    if (i >= CANON_TOTAL) return;
    const void* srcs[12] = {s0, s1, s2, s3, s4, s5, s6, s7, s8, s9, s10, s11};
    const int cnt[12] = {110592, 36864, 147456, 147456, 192, 192, 192, 192, 192, 768, 192, 1014};
    const int off[12] = {64, 221248, 294976, 589888, 884800, 885184, 885568, 885952, 886336, 886720, 888256, 888640};
    int seg = 0, base = 0;
    while (seg < 11 && i >= base + cnt[seg]) { base += cnt[seg]; seg++; }
    int j = i - base;
    const void* sp = srcs[seg];
    u16* dp = (u16*)(ws + off[seg]);
    dp[j] = (*flag) ? f2b(((const float*)sp)[j]) : ((const u16*)sp)[j];
}

// ---- LayerNorm. GATHER=1: src = d_in[0] (dtype per flag), rows via map_token.
template<int GATHER>
__global__ __launch_bounds__(256) void ln_kernel(
    const void* __restrict__ src, const u16* __restrict__ w, const u16* __restrict__ bia,
    u16* __restrict__ dst, int m_base, const int* __restrict__ flag)
{
    int wave = threadIdx.x >> 6, lane = threadIdx.x & 63;
    int mloc = blockIdx.x * 4 + wave;
    size_t row;
    if (GATHER) { int b; int l = map_token(m_base + mloc, b); row = (size_t)b * LTOK + l; }
    else row = mloc;
    float v0, v1, v2;
    if (GATHER && *flag) {
        const float* xp = (const float*)src + row * CCH;
        v0 = xp[lane]; v1 = xp[lane + 64]; v2 = xp[lane + 128];
    } else {
        const u16* xp = (const u16*)src + row * CCH;
        v0 = b2f(xp[lane]); v1 = b2f(xp[lane + 64]); v2 = b2f(xp[lane + 128]);
    }
    float s = v0 + v1 + v2, sq = v0 * v0 + v1 * v1 + v2 * v2;
    for (int off = 32; off > 0; off >>= 1) {
        s  += __shfl_xor(s, off, 64);
        sq += __shfl_xor(sq, off, 64);
    }
    float mean = s * (1.f / 192.f);
    float var  = fmaxf(sq * (1.f / 192.f) - mean * mean, 0.f);
    float rstd = rsqrtf(var + 1e-5f);
    u16* op = dst + (size_t)mloc * CCH;
    op[lane]       = f2b((v0 - mean) * rstd * b2f(w[lane])       + b2f(bia[lane]));
    op[lane + 64]  = f2b((v1 - mean) * rstd * b2f(w[lane + 64])  + b2f(bia[lane + 64]));
    op[lane + 128] = f2b((v2 - mean) * rstd * b2f(w[lane + 128]) + b2f(bia[lane + 128]));
}

// ---- DMA-stage a ROWSx32 bf16 chunk (row stride ldk u16) into LINEAR LDS
// [ROWS][32] with T2-style chunk swizzle: within each 64B row (4x16B chunks),
// lds chunk c holds global chunk c ^ ((row>>1)&3). Pre-swizzled on the GLOBAL
// source (rule #21); read side applies the same XOR. Uniform: EXACTLY
// ROWS*4/256 loads per thread (A:2, B:3) -> exact counted vmcnt.
template<int ROWS>
__device__ __forceinline__ void stageL(const u16* __restrict__ g, int ldk, u16* s, int tid) {
    constexpr int ITER = ROWS * 4 / 256;
    #pragma unroll
    for (int it = 0; it < ITER; it++) {
        int t = it * 256 + tid;
        int row = t >> 2, c = t & 3;
        int cc = c ^ ((row >> 1) & 3);
        const u16* src = g + (size_t)row * ldk + cc * 8;
        u16* dst = s + (size_t)(it * 256 + (tid & ~63)) * 8;   // wave base
        __builtin_amdgcn_global_load_lds(
            (const __attribute__((address_space(1))) void*)src,
            (__attribute__((address_space(3))) void*)dst, 16, 0, 0);
    }
}

// ---- Uniform GEMM, depth-2 counted-vmcnt pipeline: block = 128M x 192N,
// BK=32, THREE LDS buffers (61.4KB -> 2 blocks/CU). Prologue stages t=0,1,2;
// steady state per step: vmcnt(10) [wait stage(t), leave t+1,t+2 IN FLIGHT]
// -> barrier -> ds_read + 96 MFMA -> barrier -> issue stage(t+3) into the
// just-freed buffer. Load latency tolerance = 2 full steps.
// MODE 0: qkv -> Cb (stride 576). MODE 1: proj+bias+residual scatter -> X1.
// MODE 2: fc1+bias+gelu -> Cb (stride 768). MODE 3: fc2+bias+gelu+res -> Oout.
template<int MODE, int KK>
__global__ __launch_bounds__(256, 2) void gemm_t(
    const u16* __restrict__ A, const u16* __restrict__ Bm,
    const u16* __restrict__ bias,
    u16* __restrict__ Cb, u16* __restrict__ X1, const void* __restrict__ Xin,
    void* __restrict__ Oout, size_t o_off, int m_base,
    const int* __restrict__ flag)
{
    __shared__ __align__(16) u16 As[3][128 * 32];
    __shared__ __align__(16) u16 Bs[3][192 * 32];
    int tid = threadIdx.x;
    int m0 = blockIdx.x * 128, n0 = blockIdx.y * 192;
    int wave = tid >> 6, lane = tid & 63;
    int wm = wave >> 1, wn = wave & 1;
    int quad = lane >> 4, mr = lane & 15;

    const u16* Ag = A + (size_t)m0 * KK;
    const u16* Bg = Bm + (size_t)n0 * KK;

    constexpr int NSTEP = KK / 32;

    // prologue: 3 stages in flight (NSTEP >= 6 always here)
    stageL<128>(Ag,      KK, As[0], tid);
    stageL<192>(Bg,      KK, Bs[0], tid);
    stageL<128>(Ag + 32, KK, As[1], tid);
    stageL<192>(Bg + 32, KK, Bs[1], tid);
    stageL<128>(Ag + 64, KK, As[2], tid);
    stageL<192>(Bg + 64, KK, Bs[2], tid);

    f32x4 acc[4][6] = {};

    #pragma unroll 1
    for (int t = 0; t < NSTEP; t++) {
        int cur = t % 3;
        int rem = NSTEP - t;                      // stages still unconsumed (incl. t)
        if (rem >= 3)      asm volatile("s_waitcnt vmcnt(10)"); // stage(t) landed
        else if (rem == 2) asm volatile("s_waitcnt vmcnt(5)");
        else               asm volatile("s_waitcnt vmcnt(0)");
        __builtin_amdgcn_s_barrier();
        __builtin_amdgcn_sched_barrier(0);
        b16x8 a[4], b[6];
        #pragma unroll
        for (int sm = 0; sm < 4; sm++) {
            int row = wm * 64 + sm * 16 + mr;
            a[sm] = __builtin_bit_cast(b16x8,
                *(const u16x8*)&As[cur][row * 32 + (quad ^ ((row >> 1) & 3)) * 8]);
        }
        #pragma unroll
        for (int sn = 0; sn < 6; sn++) {
            int row = wn * 96 + sn * 16 + mr;
            b[sn] = __builtin_bit_cast(b16x8,
                *(const u16x8*)&Bs[cur][row * 32 + (quad ^ ((row >> 1) & 3)) * 8]);
        }
        #pragma unroll
        for (int sm = 0; sm < 4; sm++)
            #pragma unroll
            for (int sn = 0; sn < 6; sn++)
                acc[sm][sn] = __builtin_amdgcn_mfma_f32_16x16x32_bf16(a[sm], b[sn], acc[sm][sn], 0, 0, 0);
        __builtin_amdgcn_sched_barrier(0);
        __builtin_amdgcn_s_barrier();             // all waves done reading buf cur
        if (t + 3 < NSTEP) {                      // refill the just-freed buffer
            stageL<128>(Ag + (t + 3) * 32, KK, As[cur], tid);
            stageL<192>(Bg + (t + 3) * 32, KK, Bs[cur], tid);
        }
        __builtin_amdgcn_sched_barrier(0);
    }

    int isf = *flag;
    #pragma unroll
    for (int sm = 0; sm < 4; sm++) {
        #pragma unroll
        for (int r = 0; r < 4; r++) {
            int mm = m0 + wm * 64 + sm * 16 + quad * 4 + r;
            int bimg = 0, limg = 0;
            if (MODE == 1) { limg = map_token(m_base + mm, bimg); }
            #pragma unroll
            for (int sn = 0; sn < 6; sn++) {
                float val = acc[sm][sn][r];
                int nn = n0 + wn * 96 + sn * 16 + mr;
                if (MODE == 0) {
                    Cb[(size_t)mm * 576 + nn] = f2b(val);
                } else if (MODE == 1) {
                    val += b2f(bias[nn]);
                    size_t idx = ((size_t)bimg * LTOK + limg) * CCH + nn;
                    float xi = isf ? ((const float*)Xin)[idx] : b2f(((const u16*)Xin)[idx]);
                    X1[idx] = f2b(xi + val);
                } else if (MODE == 2) {
                    val = gelu_exact(val + b2f(bias[nn]));
                    Cb[(size_t)mm * 768 + nn] = f2b(val);
                } else {
                    val = gelu_exact(val + b2f(bias[nn]));
                    size_t idx = (size_t)mm * CCH + nn;
                    float r2 = val + b2f(X1[idx]);
                    if (isf) ((float*)Oout)[o_off + idx] = r2;
                    else     ((u16*)Oout)[o_off + idx]  = f2b(r2);
                }
            }
        }
    }
}

// ---- MFMA attention (unchanged, verified)
__global__ __launch_bounds__(256) void attn_kernel(
    const u16* __restrict__ qkv, const u16* __restrict__ rel_bias,
    u16* __restrict__ aout)
{
    __shared__ __align__(16) u16 qs[64 * 32];
    __shared__ __align__(16) u16 ks[64 * 32];
    __shared__ __align__(16) u16 vsT[32 * 72];
    __shared__ __align__(16) u16 ps[64 * 72];
    __shared__ float bias_s[169];
    int blk = blockIdx.x;
    int widx = blk / NHEAD, head = blk - widx * NHEAD;
    int wloc = widx & 63;
    int wh = wloc >> 3, ww = wloc & 7;
    int tid = threadIdx.x;
    const u16* base = qkv + (size_t)widx * LW * 576 + head * HDIM;

    if (tid < 196) {
        int i = tid >> 2, c8 = (tid & 3) * 8;
        *(uint4*)&qs[i * 32 + c8] = *(const uint4*)(base + (size_t)i * 576 + c8);
        *(uint4*)&ks[i * 32 + c8] = *(const uint4*)(base + (size_t)i * 576 + 192 + c8);
        u16x8 vv = *(const u16x8*)(base + (size_t)i * 576 + 384 + c8);
        #pragma unroll
        for (int q = 0; q < 8; q++) vsT[(c8 + q) * 72 + i] = vv[q];
    }
    for (int idx = tid; idx < 32 * 15; idx += 256) {   // zero pad cols 49..63
        int d = idx / 15, j = 49 + (idx - d * 15);
        vsT[d * 72 + j] = 0;
    }
    if (tid < 169) bias_s[tid] = b2f(rel_bias[tid * NHEAD + head]);
    __syncthreads();

    int wave = tid >> 6, lane = tid & 63;
    int quad = lane >> 4, c = lane & 15;

    b16x8 aq = __builtin_bit_cast(b16x8, *(const u16x8*)&qs[(wave * 16 + c) * 32 + quad * 8]);
    f32x4 sacc[4];
    #pragma unroll
    for (int nt = 0; nt < 4; nt++) {
        b16x8 bk = __builtin_bit_cast(b16x8, *(const u16x8*)&ks[(nt * 16 + c) * 32 + quad * 8]);
        f32x4 z = {};
        sacc[nt] = __builtin_amdgcn_mfma_f32_16x16x32_bf16(aq, bk, z, 0, 0, 0);
    }

    const float SCALE = 13.856406460551018f;
    float val[4][4];
    int rbase = wave * 16 + quad * 4;
    #pragma unroll
    for (int r = 0; r < 4; r++) {
        int i = rbase + r;
        int ih = i / WS7, iw = i - ih * WS7;
        int ri = (wh == 7 ? (ih < 4 ? 1 : 2) : 0) * 3 + (ww == 7 ? (iw < 4 ? 1 : 2) : 0);
        #pragma unroll
        for (int nt = 0; nt < 4; nt++) {
            int j = nt * 16 + c;
            float v;
            if (i >= LW) v = 0.f;
            else if (j >= LW) v = -1e30f;
            else {
                int jh = j / WS7, jw = j - jh * WS7;
                int rj = (wh == 7 ? (jh < 4 ? 1 : 2) : 0) * 3 + (ww == 7 ? (jw < 4 ? 1 : 2) : 0);
                if (ri != rj) v = -100.0f;
                else v = fmaf(sacc[nt][r], SCALE, bias_s[(ih - jh + 6) * 13 + (iw - jw + 6)]);
            }
            val[r][nt] = v;
        }
    }

    #pragma unroll
    for (int r = 0; r < 4; r++) {
        float mx = fmaxf(fmaxf(val[r][0], val[r][1]), fmaxf(val[r][2], val[r][3]));
        for (int d = 1; d < 16; d <<= 1) mx = fmaxf(mx, __shfl_xor(mx, d, 64));
        float sum = 0.f;
        #pragma unroll
        for (int nt = 0; nt < 4; nt++) { float e = expf(val[r][nt] - mx); val[r][nt] = e; sum += e; }
        for (int d = 1; d < 16; d <<= 1) sum += __shfl_xor(sum, d, 64);
        float inv = 1.f / sum;
        int i = rbase + r;
        #pragma unroll
        for (int nt = 0; nt < 4; nt++)
            ps[i * 72 + nt * 16 + c] = f2b(val[r][nt] * inv);
    }

    f32x4 oacc[2] = {{}, {}};
    #pragma unroll
    for (int kh = 0; kh < 2; kh++) {
        b16x8 ap = __builtin_bit_cast(b16x8, *(const u16x8*)&ps[(wave * 16 + c) * 72 + kh * 32 + quad * 8]);
        #pragma unroll
        for (int nt = 0; nt < 2; nt++) {
            b16x8 bv = __builtin_bit_cast(b16x8, *(const u16x8*)&vsT[(nt * 16 + c) * 72 + kh * 32 + quad * 8]);
            oacc[nt] = __builtin_amdgcn_mfma_f32_16x16x32_bf16(ap, bv, oacc[nt], 0, 0, 0);
        }
    }
    #pragma unroll
    for (int nt = 0; nt < 2; nt++) {
        #pragma unroll
        for (int r = 0; r < 4; r++) {
            int i = rbase + r;
            if (i < LW)
                aout[((size_t)widx * LW + i) * CCH + head * HDIM + nt * 16 + c] = f2b(oacc[nt][r]);
        }
    }
}

extern "C" void kernel_launch(void* const* d_in, const int* in_sizes, int n_in,
                              void* d_out, int out_size, void* d_ws, size_t ws_size,
                              hipStream_t stream)
{
    const void* x_in = d_in[0];
    char* ws = (char*)d_ws;
    int* flag = (int*)ws;

    u16* qkvw_c  = (u16*)(ws + 64);
    u16* projw_c = (u16*)(ws + 221248);
    u16* fc1w_c  = (u16*)(ws + 294976);
    u16* fc2w_c  = (u16*)(ws + 589888);
    u16* n1w_c   = (u16*)(ws + 884800);
    u16* n1b_c   = (u16*)(ws + 885184);
    u16* n2w_c   = (u16*)(ws + 885568);
    u16* n2b_c   = (u16*)(ws + 885952);
    u16* projb_c = (u16*)(ws + 886336);
    u16* fc1b_c  = (u16*)(ws + 886720);
    u16* fc2b_c  = (u16*)(ws + 888256);
    u16* relb_c  = (u16*)(ws + 888640);

    const size_t P0 = 1u << 20;
    const size_t X1SZ   = (size_t)MTOK * CCH * 2;   //  38,535,168
    const size_t QKVSZ  = (size_t)MTOK * 576 * 2;   // 115,605,504

    u16* x1 = (u16*)(ws + P0);

    probe_kernel<<<1, 1024, 0, stream>>>((const u16*)x_in, flag);
    canon_all_kernel<<<(CANON_TOTAL + 255) / 256, 256, 0, stream>>>(
        flag,
        d_in[7], d_in[9], d_in[13], d_in[15],
        d_in[5], d_in[6], d_in[11], d_in[12],
        d_in[10], d_in[14], d_in[16], d_in[8],
        ws);

    if (ws_size >= P0 + 3 * X1SZ + QKVSZ) {
        // ---- big tier. Layout: x1 | winq(xn) | aout | qkvq ; h1 aliases aout+qkvq.
        u16* winq = (u16*)(ws + P0 + X1SZ);
        u16* aout = (u16*)(ws + P0 + 2 * X1SZ);
        u16* qkvq = (u16*)(ws + P0 + 3 * X1SZ);
        u16* h1q  = aout;   // 154.1 MB = aout(38.5) + qkvq(115.6), both dead by fc1

        ln_kernel<1><<<MTOK / 4, 256, 0, stream>>>(x_in, n1w_c, n1b_c, winq, 0, flag);
        gemm_t<0, 192><<<dim3(MTOK / 128, 3), 256, 0, stream>>>(
            winq, qkvw_c, nullptr, qkvq, nullptr, nullptr, nullptr, 0, 0, flag);
        attn_kernel<<<NWTOT * NHEAD, 256, 0, stream>>>(qkvq, relb_c, aout);
        gemm_t<1, 192><<<dim3(MTOK / 128, 1), 256, 0, stream>>>(
            aout, projw_c, projb_c, nullptr, x1, x_in, nullptr, 0, 0, flag);
        ln_kernel<0><<<MTOK / 4, 256, 0, stream>>>(x1, n2w_c, n2b_c, winq, 0, flag);
        gemm_t<2, 192><<<dim3(MTOK / 128, 4), 256, 0, stream>>>(
            winq, fc1w_c, fc1b_c, h1q, nullptr, nullptr, nullptr, 0, 0, flag);
        gemm_t<3, 768><<<dim3(MTOK / 128, 1), 256, 0, stream>>>(
            h1q, fc2w_c, fc2b_c, nullptr, x1, nullptr, d_out, 0, 0, flag);
    } else {
        // ---- small tier (<=78 MB scratch): 8-way chunked both phases.
        const int QC = 8, EC = 8;
        const int MQ = MTOK / QC, ME = MTOK / EC;    // 12544 = 98*128
        u16* winq = (u16*)(ws + P0 + X1SZ);                       // 4.8 MB
        u16* aout = (u16*)(ws + P0 + X1SZ + (size_t)MQ * CCH * 2);
        u16* qkvq = (u16*)(ws + P0 + X1SZ + 2 * (size_t)MQ * CCH * 2);
        u16* h1q  = winq;    // 19.3 MB aliases winq+aout+qkvq region in MLP phase

        for (int q = 0; q < QC; q++) {
            int mb = q * MQ;
            ln_kernel<1><<<MQ / 4, 256, 0, stream>>>(x_in, n1w_c, n1b_c, winq, mb, flag);
            gemm_t<0, 192><<<dim3(MQ / 128, 3), 256, 0, stream>>>(
                winq, qkvw_c, nullptr, qkvq, nullptr, nullptr, nullptr, 0, mb, flag);
            attn_kernel<<<(NWTOT / QC) * NHEAD, 256, 0, stream>>>(qkvq, relb_c, aout);
            gemm_t<1, 192><<<dim3(MQ / 128, 1), 256, 0, stream>>>(
                aout, projw_c, projb_c, nullptr, x1, x_in, nullptr, 0, mb, flag);
        }
        u16* xnq = (u16*)(ws + P0 + X1SZ + (size_t)ME * 768 * 2);  // after h1
        for (int e = 0; e < EC; e++) {
            size_t off = (size_t)e * ME * CCH;
            ln_kernel<0><<<ME / 4, 256, 0, stream>>>(x1 + off, n2w_c, n2b_c, xnq, 0, flag);
            gemm_t<2, 192><<<dim3(ME / 128, 4), 256, 0, stream>>>(
                xnq, fc1w_c, fc1b_c, h1q, nullptr, nullptr, nullptr, 0, 0, flag);
            gemm_t<3, 768><<<dim3(ME / 128, 1), 256, 0, stream>>>(
                h1q, fc2w_c, fc2b_c, nullptr, x1 + off, nullptr, d_out, off, 0, flag);
        }
    }
}